// Round 1
// baseline (2431.701 us; speedup 1.0000x reference)
//
#include <hip/hip_runtime.h>
#include <hip/hip_bf16.h>

#define DIM 192
#define HEADS 6
#define HD 32
#define NTOK 64
#define BATCH 2048
#define CPBH 512
#define TBL 343

typedef unsigned int u32;

__device__ __forceinline__ float bflo(u32 u) { return __uint_as_float(u << 16); }
__device__ __forceinline__ float bfhi(u32 u) { return __uint_as_float(u & 0xffff0000u); }
__device__ __forceinline__ unsigned short f2bf(float f) {
  union { __hip_bfloat16 h; unsigned short s; } cv;
  cv.h = __float2bfloat16(f);
  return cv.s;
}
__device__ __forceinline__ u32 pack2(float a, float b) {
  return (u32)f2bf(a) | ((u32)f2bf(b) << 16);
}

// ---------- CPB MLP: (343,3) -> relu(512) -> (343,6) ----------
__global__ void k_cpb1(const float* __restrict__ rpb, const float* __restrict__ w1,
                       const float* __restrict__ b1, const float* __restrict__ w2,
                       float* __restrict__ tab) {
  int idx = blockIdx.x * blockDim.x + threadIdx.x;
  if (idx >= TBL * HEADS) return;
  int t = idx / HEADS, h = idx % HEADS;
  float r0 = rpb[t*3], r1 = rpb[t*3+1], r2 = rpb[t*3+2];
  float acc = 0.f;
  for (int k = 0; k < CPBH; ++k) {
    float hv = r0*w1[k*3] + r1*w1[k*3+1] + r2*w1[k*3+2] + b1[k];
    hv = fmaxf(hv, 0.f);
    acc += hv * w2[h*CPBH + k];
  }
  tab[idx] = acc;
}

// ---------- expand table via rpb_idx, apply 16*sigmoid -> (H,64,64) ----------
__global__ void k_cpb2(const float* __restrict__ tab, const int* __restrict__ ridx,
                       float* __restrict__ full) {
  int idx = blockIdx.x * blockDim.x + threadIdx.x; // h*4096 + i*64 + j
  if (idx >= HEADS * 4096) return;
  int h = idx >> 12, ij = idx & 4095;
  float v = tab[ridx[ij] * HEADS + h];
  full[idx] = 16.f / (1.f + expf(-v));
}

// ---------- QKV projection + cosine-normalize q,k; bf16 out (B,H,N,32) ----------
__global__ __launch_bounds__(384) void k_qkv(
    const float* __restrict__ x, const float* __restrict__ w,
    const float* __restrict__ bqkv,
    u32* __restrict__ qo, u32* __restrict__ ko, u32* __restrict__ vo) {
  __shared__ float xl[DIM * 65];   // [k][n], pad 65 -> conflict-free lane=n reads
  const int tid = threadIdx.x;
  const int b = blockIdx.x;
  const float4* xg = (const float4*)(x + (size_t)b * (NTOK * DIM));
  for (int i = tid; i < (NTOK * DIM) / 4; i += 384) {
    float4 vv = xg[i];
    int flat = i * 4;
    int n = flat / DIM, k0 = flat % DIM;
    xl[(k0+0)*65 + n] = vv.x;
    xl[(k0+1)*65 + n] = vv.y;
    xl[(k0+2)*65 + n] = vv.z;
    xl[(k0+3)*65 + n] = vv.w;
  }
  __syncthreads();
  const int lane = tid & 63;   // = n (row)
  const int wv = tid >> 6;     // wave 0..5
  #pragma unroll 1
  for (int c = 0; c < 3; ++c) {
    int combo = wv * 3 + c;            // 0..17 = (sel,h), wave-uniform
    int sel = combo / HEADS;
    int h = combo % HEADS;
    int j0 = __builtin_amdgcn_readfirstlane(sel * DIM + h * HD);
    float acc[32];
    #pragma unroll
    for (int d = 0; d < 32; ++d) acc[d] = 0.f;
    #pragma unroll 1
    for (int kt = 0; kt < DIM; kt += 32) {
      float xr[32];
      #pragma unroll
      for (int kk = 0; kk < 32; ++kk) xr[kk] = xl[(kt + kk) * 65 + lane];
      #pragma unroll
      for (int d = 0; d < 32; ++d) {
        const float* wp = w + (size_t)(j0 + d) * DIM + kt;  // uniform -> s_load
        #pragma unroll
        for (int kk = 0; kk < 32; ++kk) acc[d] = fmaf(xr[kk], wp[kk], acc[d]);
      }
    }
    #pragma unroll
    for (int d = 0; d < 32; ++d) acc[d] += bqkv[j0 + d];
    if (sel < 2) {  // cosine norm for q,k
      float ss = 0.f;
      #pragma unroll
      for (int d = 0; d < 32; ++d) ss = fmaf(acc[d], acc[d], ss);
      float inv = 1.f / fmaxf(sqrtf(ss), 1e-12f);
      #pragma unroll
      for (int d = 0; d < 32; ++d) acc[d] *= inv;
    }
    u32* dst = (sel == 0) ? qo : (sel == 1) ? ko : vo;
    size_t off16 = (((size_t)b * HEADS + h) * NTOK + lane) * (HD / 2);
    u32 pk[16];
    #pragma unroll
    for (int p = 0; p < 16; ++p) pk[p] = pack2(acc[2*p], acc[2*p+1]);
    uint4* d4 = (uint4*)(dst + off16);
    d4[0] = make_uint4(pk[0],  pk[1],  pk[2],  pk[3]);
    d4[1] = make_uint4(pk[4],  pk[5],  pk[6],  pk[7]);
    d4[2] = make_uint4(pk[8],  pk[9],  pk[10], pk[11]);
    d4[3] = make_uint4(pk[12], pk[13], pk[14], pk[15]);
  }
}

// ---------- attention per (b,h): S=qn@knT*scale+bias+mask, softmax, @v ----------
__global__ __launch_bounds__(256) void k_attn(
    const u32* __restrict__ qg, const u32* __restrict__ kg, const u32* __restrict__ vg,
    const float* __restrict__ biasFull, const float* __restrict__ mask,
    const float* __restrict__ ls, u32* __restrict__ ao) {
  __shared__ u32 qs[1024], ks[1024], vs[1024];  // 64x32 bf16 each
  __shared__ float bm[64 * 65];
  const int tid = threadIdx.x;
  const int h = blockIdx.x % HEADS;
  const int b = blockIdx.x / HEADS;
  size_t base32 = ((size_t)b * HEADS + h) * 1024;
  const uint2* q2 = (const uint2*)(qg + base32);
  const uint2* k2 = (const uint2*)(kg + base32);
  const uint2* v2 = (const uint2*)(vg + base32);
  ((uint2*)qs)[tid] = q2[tid]; ((uint2*)qs)[tid+256] = q2[tid+256];
  ((uint2*)ks)[tid] = k2[tid]; ((uint2*)ks)[tid+256] = k2[tid+256];
  ((uint2*)vs)[tid] = v2[tid]; ((uint2*)vs)[tid+256] = v2[tid+256];
  const float* bp = biasFull + h * 4096;
  const float* mp = mask + (size_t)(b & 63) * 4096;
  for (int i = tid; i < 4096; i += 256)
    bm[(i >> 6) * 65 + (i & 63)] = bp[i] + mp[i];
  __syncthreads();

  const int row = tid >> 2;   // 0..63
  const int tq = tid & 3;     // 4 threads per row, j = tq + 4*jj
  float qf[32];
  #pragma unroll
  for (int u = 0; u < 16; ++u) {
    u32 q = qs[row * 16 + u];
    qf[2*u] = bflo(q); qf[2*u+1] = bfhi(q);
  }
  const float scale = __expf(fminf(ls[h], 4.6051702f)); // clamp at log(100)
  float sv[16];
  #pragma unroll
  for (int jj = 0; jj < 16; ++jj) {
    int j = tq + jj * 4;
    float s = 0.f;
    #pragma unroll
    for (int u = 0; u < 16; ++u) {
      u32 kk = ks[j * 16 + u];
      s = fmaf(qf[2*u], bflo(kk), s);
      s = fmaf(qf[2*u+1], bfhi(kk), s);
    }
    sv[jj] = fmaf(s, scale, bm[row * 65 + j]);
  }
  float m = sv[0];
  #pragma unroll
  for (int jj = 1; jj < 16; ++jj) m = fmaxf(m, sv[jj]);
  m = fmaxf(m, __shfl_xor(m, 1));
  m = fmaxf(m, __shfl_xor(m, 2));
  float l = 0.f;
  #pragma unroll
  for (int jj = 0; jj < 16; ++jj) { sv[jj] = __expf(sv[jj] - m); l += sv[jj]; }
  l += __shfl_xor(l, 1);
  l += __shfl_xor(l, 2);
  const float rinv = 1.f / l;
  float o[32];
  #pragma unroll
  for (int d = 0; d < 32; ++d) o[d] = 0.f;
  #pragma unroll
  for (int jj = 0; jj < 16; ++jj) {
    int j = tq + jj * 4;
    float p = sv[jj];
    #pragma unroll
    for (int u = 0; u < 16; ++u) {
      u32 vv = vs[j * 16 + u];
      o[2*u]   = fmaf(p, bflo(vv), o[2*u]);
      o[2*u+1] = fmaf(p, bfhi(vv), o[2*u+1]);
    }
  }
  #pragma unroll
  for (int d = 0; d < 32; ++d) {
    float t = o[d];
    t += __shfl_xor(t, 1);
    t += __shfl_xor(t, 2);
    o[d] = t * rinv;
  }
  // this thread writes d in [tq*8, tq*8+8) -> select without dynamic reg index
  u32 pk[4];
  #pragma unroll
  for (int e = 0; e < 4; ++e) {
    float a0 = (tq==0) ? o[2*e]   : (tq==1) ? o[8+2*e]   : (tq==2) ? o[16+2*e]   : o[24+2*e];
    float a1 = (tq==0) ? o[2*e+1] : (tq==1) ? o[8+2*e+1] : (tq==2) ? o[16+2*e+1] : o[24+2*e+1];
    pk[e] = pack2(a0, a1);
  }
  size_t ob = (((size_t)b * NTOK + row) * DIM + h * HD + tq * 8) / 2;
  *(uint4*)(ao + ob) = make_uint4(pk[0], pk[1], pk[2], pk[3]);
}

// ---------- output projection: (B*N,192)bf16 @ (192,192)T + b -> fp32 ----------
__global__ __launch_bounds__(384) void k_proj(
    const u32* __restrict__ ao, const float* __restrict__ pw,
    const float* __restrict__ pb, float* __restrict__ out) {
  __shared__ float al[DIM * 65];
  const int tid = threadIdx.x;
  const int b = blockIdx.x;
  const u32* ag = ao + (size_t)b * (NTOK * DIM / 2);
  for (int i = tid; i < NTOK * DIM / 2; i += 384) {
    u32 a = ag[i];
    int flat = i * 2;
    int n = flat / DIM, k0 = flat % DIM;
    al[(k0+0)*65 + n] = bflo(a);
    al[(k0+1)*65 + n] = bfhi(a);
  }
  __syncthreads();
  const int lane = tid & 63;
  const int wv = tid >> 6;
  const int j0 = __builtin_amdgcn_readfirstlane(wv * 32);
  float acc[32];
  #pragma unroll
  for (int d = 0; d < 32; ++d) acc[d] = 0.f;
  #pragma unroll 1
  for (int kt = 0; kt < DIM; kt += 32) {
    float xr[32];
    #pragma unroll
    for (int kk = 0; kk < 32; ++kk) xr[kk] = al[(kt + kk) * 65 + lane];
    #pragma unroll
    for (int d = 0; d < 32; ++d) {
      const float* wp = pw + (size_t)(j0 + d) * DIM + kt;
      #pragma unroll
      for (int kk = 0; kk < 32; ++kk) acc[d] = fmaf(xr[kk], wp[kk], acc[d]);
    }
  }
  #pragma unroll
  for (int d = 0; d < 32; ++d) acc[d] += pb[j0 + d];
  float* op = out + ((size_t)b * NTOK + lane) * DIM + j0;
  #pragma unroll
  for (int e = 0; e < 8; ++e)
    *(float4*)(op + 4*e) = make_float4(acc[4*e], acc[4*e+1], acc[4*e+2], acc[4*e+3]);
}

extern "C" void kernel_launch(void* const* d_in, const int* in_sizes, int n_in,
                              void* d_out, int out_size, void* d_ws, size_t ws_size,
                              hipStream_t stream) {
  const float* x    = (const float*)d_in[0];
  const float* mask = (const float*)d_in[1];
  const float* rpb  = (const float*)d_in[2];
  const int*   ridx = (const int*)d_in[3];
  const float* w1   = (const float*)d_in[4];
  const float* b1   = (const float*)d_in[5];
  const float* w2   = (const float*)d_in[6];
  const float* qkvw = (const float*)d_in[7];
  const float* qkvb = (const float*)d_in[8];
  const float* pw   = (const float*)d_in[9];
  const float* pb   = (const float*)d_in[10];
  const float* ls   = (const float*)d_in[11];
  float* out = (float*)d_out;

  char* ws = (char*)d_ws;
  const size_t QS = (size_t)BATCH * HEADS * NTOK * HD * 2;  // 50,331,648 B per array
  u32* qo = (u32*)(ws);
  u32* ko = (u32*)(ws + QS);
  u32* vo = (u32*)(ws + 2 * QS);
  u32* ao = (u32*)(ws + 3 * QS);
  float* btab  = (float*)(ws + 4 * QS);
  float* bfull = (float*)(ws + 4 * QS + 16384);
  // total ws use: 4*50331648 + 16384 + 98304 = 201,441,280 bytes

  k_cpb1<<<(TBL * HEADS + 255) / 256, 256, 0, stream>>>(rpb, w1, b1, w2, btab);
  k_cpb2<<<(HEADS * 4096) / 256, 256, 0, stream>>>(btab, ridx, bfull);
  k_qkv<<<BATCH, 384, 0, stream>>>(x, qkvw, qkvb, qo, ko, vo);
  k_attn<<<BATCH * HEADS, 256, 0, stream>>>(qo, ko, vo, bfull, mask, ls, ao);
  k_proj<<<BATCH, 384, 0, stream>>>(ao, pw, pb, out);
}

// Round 2
// 525.877 us; speedup vs baseline: 4.6241x; 4.6241x over previous
//
#include <hip/hip_runtime.h>
#include <hip/hip_bf16.h>

#define DIM 192
#define HEADS 6
#define HD 32
#define NTOK 64
#define BATCH 2048
#define CPBH 512
#define TBL 343

typedef unsigned int u32;
typedef __attribute__((ext_vector_type(8))) short b16x8;
typedef __attribute__((ext_vector_type(4))) float f32x4;

__device__ __forceinline__ unsigned short f2bf(float f) {
  union { __hip_bfloat16 h; unsigned short s; } cv;
  cv.h = __float2bfloat16(f);
  return cv.s;
}
__device__ __forceinline__ u32 pack2(float a, float b) {
  return (u32)f2bf(a) | ((u32)f2bf(b) << 16);
}
union FragU { u32 u[4]; b16x8 s; uint4 q; };

__device__ __forceinline__ b16x8 ld_frag_g(const u32* p) {
  FragU f; f.q = *(const uint4*)p; return f.s;
}

// ---------- CPB MLP: one wave per table row ----------
__global__ __launch_bounds__(64) void k_cpb1(
    const float* __restrict__ rpb, const float* __restrict__ w1,
    const float* __restrict__ b1, const float* __restrict__ w2,
    float* __restrict__ tab) {
  int t = blockIdx.x, lane = threadIdx.x;
  float r0 = rpb[t*3], r1 = rpb[t*3+1], r2 = rpb[t*3+2];
  float a[HEADS];
  #pragma unroll
  for (int h = 0; h < HEADS; ++h) a[h] = 0.f;
  #pragma unroll
  for (int kk = 0; kk < 8; ++kk) {
    int k = lane * 8 + kk;
    float hv = fmaf(r0, w1[k*3], fmaf(r1, w1[k*3+1], fmaf(r2, w1[k*3+2], b1[k])));
    hv = fmaxf(hv, 0.f);
    #pragma unroll
    for (int h = 0; h < HEADS; ++h) a[h] = fmaf(hv, w2[h*CPBH + k], a[h]);
  }
  #pragma unroll
  for (int h = 0; h < HEADS; ++h) {
    a[h] += __shfl_xor(a[h], 1);  a[h] += __shfl_xor(a[h], 2);
    a[h] += __shfl_xor(a[h], 4);  a[h] += __shfl_xor(a[h], 8);
    a[h] += __shfl_xor(a[h], 16); a[h] += __shfl_xor(a[h], 32);
  }
  if (lane == 0) {
    #pragma unroll
    for (int h = 0; h < HEADS; ++h) tab[t*HEADS + h] = a[h];
  }
}

// ---------- expand bias table: 16*sigmoid, (H,64,64) fp32 ----------
__global__ void k_cpb2(const float* __restrict__ tab, const int* __restrict__ ridx,
                       float* __restrict__ full) {
  int idx = blockIdx.x * blockDim.x + threadIdx.x;
  if (idx >= HEADS * 4096) return;
  int h = idx >> 12, ij = idx & 4095;
  float v = tab[ridx[ij] * HEADS + h];
  full[idx] = 16.f / (1.f + __expf(-v));
}

// ---------- QKV: MFMA, transposed mapping (A=W rows, B=x^T) ----------
// out q,k: (b,h,tok,32) bf16 normalized; v: (b,h,d,tok) bf16 transposed
__global__ __launch_bounds__(384) void k_qkv(
    const float* __restrict__ x, const float* __restrict__ w,
    const float* __restrict__ bias,
    u32* __restrict__ qo, u32* __restrict__ ko, u32* __restrict__ vT) {
  __shared__ u32 xl[NTOK * 100];   // 64 rows x 200 bf16 (stride 100 dwords)
  const int tid = threadIdx.x;
  const int b = blockIdx.x;
  // stage x -> bf16 LDS, token-major
  const float4* xg = (const float4*)(x + (size_t)b * (NTOK * DIM));
  for (int i = tid; i < (NTOK * DIM) / 4; i += 384) {
    float4 v = xg[i];
    int flat = i * 4, tok = flat / DIM, k = flat % DIM;
    xl[tok*100 + k/2]     = pack2(v.x, v.y);
    xl[tok*100 + k/2 + 1] = pack2(v.z, v.w);
  }
  __syncthreads();
  const int lane = tid & 63;
  const int wv = tid >> 6;         // 0..5
  const int m = lane & 15;
  const int qd = lane >> 4;        // quad 0..3
  const int sel = wv >> 1;         // 0=q 1=k 2=v (wave-uniform)
  u32* dst = (sel == 0) ? qo : (sel == 1) ? ko : vT;
  #pragma unroll 1
  for (int p = 0; p < 3; ++p) {
    const int h = (wv & 1) * 3 + p;
    const int jbase = wv * 96 + p * 32;
    // A fragments: W rows jbase..jbase+31, inline fp32->bf16
    b16x8 afr[2][6];
    float bv[2][4];
    #pragma unroll
    for (int half = 0; half < 2; ++half) {
      const float* wp = w + (size_t)(jbase + half*16 + m) * DIM;
      #pragma unroll
      for (int ks = 0; ks < 6; ++ks) {
        float4 f0 = *(const float4*)(wp + ks*32 + qd*8);
        float4 f1 = *(const float4*)(wp + ks*32 + qd*8 + 4);
        FragU fu;
        fu.u[0] = pack2(f0.x, f0.y); fu.u[1] = pack2(f0.z, f0.w);
        fu.u[2] = pack2(f1.x, f1.y); fu.u[3] = pack2(f1.z, f1.w);
        afr[half][ks] = fu.s;
      }
      #pragma unroll
      for (int r = 0; r < 4; ++r) bv[half][r] = bias[jbase + half*16 + qd*4 + r];
    }
    const size_t bh1024 = ((size_t)b * HEADS + h) * 1024;
    #pragma unroll 1
    for (int t = 0; t < 4; ++t) {
      f32x4 acc0 = {0.f,0.f,0.f,0.f}, acc1 = {0.f,0.f,0.f,0.f};
      #pragma unroll
      for (int ks = 0; ks < 6; ++ks) {
        b16x8 bfr = *(const b16x8*)(&xl[(t*16 + m)*100 + ks*16 + qd*4]);
        acc0 = __builtin_amdgcn_mfma_f32_16x16x32_bf16(afr[0][ks], bfr, acc0, 0,0,0);
        acc1 = __builtin_amdgcn_mfma_f32_16x16x32_bf16(afr[1][ks], bfr, acc1, 0,0,0);
      }
      #pragma unroll
      for (int r = 0; r < 4; ++r) { acc0[r] += bv[0][r]; acc1[r] += bv[1][r]; }
      if (sel < 2) {
        float ss = 0.f;
        #pragma unroll
        for (int r = 0; r < 4; ++r) ss = fmaf(acc0[r],acc0[r], fmaf(acc1[r],acc1[r], ss));
        ss += __shfl_xor(ss, 16);
        ss += __shfl_xor(ss, 32);
        float inv = 1.f / fmaxf(sqrtf(ss), 1e-12f);
        #pragma unroll
        for (int r = 0; r < 4; ++r) { acc0[r] *= inv; acc1[r] *= inv; }
        // store token-major: (bh, tok, 32d) bf16 = 16 u32/token
        int tok = t*16 + m;
        u32* o = dst + bh1024 + tok*16;
        *(uint2*)(o + qd*2)     = make_uint2(pack2(acc0[0],acc0[1]), pack2(acc0[2],acc0[3]));
        *(uint2*)(o + 8 + qd*2) = make_uint2(pack2(acc1[0],acc1[1]), pack2(acc1[2],acc1[3]));
      } else {
        // v: store transposed (bh, d, tok): pack col pairs via shfl
        float p0[8];
        #pragma unroll
        for (int r = 0; r < 4; ++r) { p0[r] = acc0[r]; p0[4+r] = acc1[r]; }
        float pr[8];
        #pragma unroll
        for (int e = 0; e < 8; ++e) pr[e] = __shfl_xor(p0[e], 1);
        if ((m & 1) == 0) {
          #pragma unroll
          for (int e = 0; e < 8; ++e) {
            int d = (e >> 2)*16 + qd*4 + (e & 3);
            dst[bh1024 + d*32 + (t*16 + m)/2] = pack2(p0[e], pr[e]);
          }
        }
      }
    }
  }
}

// ---------- attention: one wave per (b,h), MFMA S and PV ----------
__global__ __launch_bounds__(384) void k_attn(
    const u32* __restrict__ qo, const u32* __restrict__ ko, const u32* __restrict__ vT,
    const float* __restrict__ bfull, const float* __restrict__ mask,
    const float* __restrict__ ls, u32* __restrict__ ao) {
  __shared__ u32 pbuf[HEADS][64 * 36];  // per-wave P, 64 rows x 72 bf16
  const int tid = threadIdx.x;
  const int b = blockIdx.x;
  const int h = tid >> 6;   // wave = head
  const int lane = tid & 63;
  const int m = lane & 15, qd = lane >> 4;
  const size_t bh1024 = ((size_t)b * HEADS + h) * 1024;

  b16x8 qfr[4], kfr[4];
  #pragma unroll
  for (int mt = 0; mt < 4; ++mt) qfr[mt] = ld_frag_g(qo + bh1024 + (mt*16 + m)*16 + qd*4);
  #pragma unroll
  for (int ct = 0; ct < 4; ++ct) kfr[ct] = ld_frag_g(ko + bh1024 + (ct*16 + m)*16 + qd*4);

  f32x4 s[4][4];
  #pragma unroll
  for (int mt = 0; mt < 4; ++mt)
    #pragma unroll
    for (int ct = 0; ct < 4; ++ct) {
      f32x4 z = {0.f,0.f,0.f,0.f};
      s[mt][ct] = __builtin_amdgcn_mfma_f32_16x16x32_bf16(qfr[mt], kfr[ct], z, 0,0,0);
    }

  const float sc = __expf(fminf(ls[h], 4.60517019f));
  const float* bp = bfull + h * 4096;
  const float* mp = mask + (size_t)(b & 63) * 4096;
  #pragma unroll
  for (int mt = 0; mt < 4; ++mt)
    #pragma unroll
    for (int ct = 0; ct < 4; ++ct) {
      #pragma unroll
      for (int r = 0; r < 4; ++r) {
        int row = mt*16 + qd*4 + r, col = ct*16 + m;
        s[mt][ct][r] = fmaf(s[mt][ct][r], sc, bp[row*64 + col] + mp[row*64 + col]);
      }
    }
  float rinv[4][4];
  u32* pb = pbuf[h];
  #pragma unroll
  for (int mt = 0; mt < 4; ++mt) {
    #pragma unroll
    for (int r = 0; r < 4; ++r) {
      float mm = s[mt][0][r];
      #pragma unroll
      for (int ct = 1; ct < 4; ++ct) mm = fmaxf(mm, s[mt][ct][r]);
      mm = fmaxf(mm, __shfl_xor(mm, 1)); mm = fmaxf(mm, __shfl_xor(mm, 2));
      mm = fmaxf(mm, __shfl_xor(mm, 4)); mm = fmaxf(mm, __shfl_xor(mm, 8));
      float l = 0.f;
      #pragma unroll
      for (int ct = 0; ct < 4; ++ct) { s[mt][ct][r] = __expf(s[mt][ct][r] - mm); l += s[mt][ct][r]; }
      l += __shfl_xor(l, 1); l += __shfl_xor(l, 2);
      l += __shfl_xor(l, 4); l += __shfl_xor(l, 8);
      rinv[mt][r] = 1.f / l;
      // write P row to LDS (bf16, packed col pairs)
      int row = mt*16 + qd*4 + r;
      #pragma unroll
      for (int ct = 0; ct < 4; ++ct) {
        float pv = s[mt][ct][r];
        float pn = __shfl_xor(pv, 1);
        if ((m & 1) == 0) pb[row*36 + ct*8 + (m >> 1)] = pack2(pv, pn);
      }
    }
  }
  // PV: A = P from LDS, B = vT fragments
  b16x8 vfr[2][2];
  #pragma unroll
  for (int nt = 0; nt < 2; ++nt)
    #pragma unroll
    for (int ks = 0; ks < 2; ++ks)
      vfr[nt][ks] = ld_frag_g(vT + bh1024 + (nt*16 + m)*32 + ks*16 + qd*4);
  #pragma unroll
  for (int mt = 0; mt < 4; ++mt) {
    b16x8 pa0 = *(const b16x8*)(&pb[(mt*16 + m)*36 + qd*4]);
    b16x8 pa1 = *(const b16x8*)(&pb[(mt*16 + m)*36 + 16 + qd*4]);
    #pragma unroll
    for (int nt = 0; nt < 2; ++nt) {
      f32x4 o = {0.f,0.f,0.f,0.f};
      o = __builtin_amdgcn_mfma_f32_16x16x32_bf16(pa0, vfr[nt][0], o, 0,0,0);
      o = __builtin_amdgcn_mfma_f32_16x16x32_bf16(pa1, vfr[nt][1], o, 0,0,0);
      #pragma unroll
      for (int r = 0; r < 4; ++r) {
        float val = o[r] * rinv[mt][r];
        float pn = __shfl_xor(val, 1);
        if ((m & 1) == 0) {
          int row = mt*16 + qd*4 + r;
          ao[((size_t)b*64 + row)*96 + h*16 + nt*8 + (m >> 1)] = pack2(val, pn);
        }
      }
    }
  }
}

// ---------- proj: MFMA, A = proj_w rows (inline cvt), B = ao^T ----------
__global__ __launch_bounds__(384) void k_proj(
    const u32* __restrict__ ao, const float* __restrict__ pw,
    const float* __restrict__ pb, float* __restrict__ out) {
  const int tid = threadIdx.x;
  const int b = blockIdx.x;
  const int wv = tid >> 6, lane = tid & 63;
  const int m = lane & 15, qd = lane >> 4;
  b16x8 afr[2][6];
  float bv[2][4];
  #pragma unroll
  for (int jj = 0; jj < 2; ++jj) {
    const float* wp = pw + (size_t)((wv*2 + jj)*16 + m) * DIM;
    #pragma unroll
    for (int ks = 0; ks < 6; ++ks) {
      float4 f0 = *(const float4*)(wp + ks*32 + qd*8);
      float4 f1 = *(const float4*)(wp + ks*32 + qd*8 + 4);
      FragU fu;
      fu.u[0] = pack2(f0.x, f0.y); fu.u[1] = pack2(f0.z, f0.w);
      fu.u[2] = pack2(f1.x, f1.y); fu.u[3] = pack2(f1.z, f1.w);
      afr[jj][ks] = fu.s;
    }
    #pragma unroll
    for (int r = 0; r < 4; ++r) bv[jj][r] = pb[(wv*2 + jj)*16 + qd*4 + r];
  }
  #pragma unroll 1
  for (int t = 0; t < 4; ++t) {
    b16x8 bfr[6];
    #pragma unroll
    for (int ks = 0; ks < 6; ++ks)
      bfr[ks] = ld_frag_g(ao + ((size_t)b*64 + t*16 + m)*96 + ks*16 + qd*4);
    f32x4 acc0 = {0.f,0.f,0.f,0.f}, acc1 = {0.f,0.f,0.f,0.f};
    #pragma unroll
    for (int ks = 0; ks < 6; ++ks) {
      acc0 = __builtin_amdgcn_mfma_f32_16x16x32_bf16(afr[0][ks], bfr[ks], acc0, 0,0,0);
      acc1 = __builtin_amdgcn_mfma_f32_16x16x32_bf16(afr[1][ks], bfr[ks], acc1, 0,0,0);
    }
    float* op = out + ((size_t)b*64 + t*16 + m) * DIM;
    *(float4*)(op + (wv*2+0)*16 + qd*4) =
        make_float4(acc0[0]+bv[0][0], acc0[1]+bv[0][1], acc0[2]+bv[0][2], acc0[3]+bv[0][3]);
    *(float4*)(op + (wv*2+1)*16 + qd*4) =
        make_float4(acc1[0]+bv[1][0], acc1[1]+bv[1][1], acc1[2]+bv[1][2], acc1[3]+bv[1][3]);
  }
}

extern "C" void kernel_launch(void* const* d_in, const int* in_sizes, int n_in,
                              void* d_out, int out_size, void* d_ws, size_t ws_size,
                              hipStream_t stream) {
  const float* x    = (const float*)d_in[0];
  const float* mask = (const float*)d_in[1];
  const float* rpb  = (const float*)d_in[2];
  const int*   ridx = (const int*)d_in[3];
  const float* w1   = (const float*)d_in[4];
  const float* b1   = (const float*)d_in[5];
  const float* w2   = (const float*)d_in[6];
  const float* qkvw = (const float*)d_in[7];
  const float* qkvb = (const float*)d_in[8];
  const float* pw   = (const float*)d_in[9];
  const float* pb   = (const float*)d_in[10];
  const float* ls   = (const float*)d_in[11];
  float* out = (float*)d_out;

  char* ws = (char*)d_ws;
  const size_t QS = (size_t)BATCH * HEADS * NTOK * HD * 2;  // 50,331,648 B
  u32* qo = (u32*)(ws);
  u32* ko = (u32*)(ws + QS);
  u32* vT = (u32*)(ws + 2 * QS);
  u32* ao = (u32*)(ws + 3 * QS);
  float* btab  = (float*)(ws + 4 * QS);
  float* bfull = (float*)(ws + 4 * QS + 16384);
  // total: 4*50331648 + 16384 + 98304 = 201,441,280 B (same as round 1)

  k_cpb1<<<TBL, 64, 0, stream>>>(rpb, w1, b1, w2, btab);
  k_cpb2<<<(HEADS * 4096 + 255) / 256, 256, 0, stream>>>(btab, ridx, bfull);
  k_qkv<<<BATCH, 384, 0, stream>>>(x, qkvw, qkvb, qo, ko, vT);
  k_attn<<<BATCH, 384, 0, stream>>>(qo, ko, vT, bfull, mask, ls, ao);
  k_proj<<<BATCH, 384, 0, stream>>>(ao, pw, pb, out);
}

// Round 3
// 418.203 us; speedup vs baseline: 5.8146x; 1.2575x over previous
//
#include <hip/hip_runtime.h>
#include <hip/hip_bf16.h>

#define DIM 192
#define HEADS 6
#define HD 32
#define NTOK 64
#define BATCH 2048
#define CPBH 512
#define TBL 343
#define NW 64

typedef unsigned int u32;
typedef __attribute__((ext_vector_type(8))) short b16x8;
typedef __attribute__((ext_vector_type(4))) float f32x4;

__device__ __forceinline__ unsigned short f2bf(float f) {
  union { __hip_bfloat16 h; unsigned short s; } cv;
  cv.h = __float2bfloat16(f);
  return cv.s;
}
__device__ __forceinline__ u32 pack2(float a, float b) {
  return (u32)f2bf(a) | ((u32)f2bf(b) << 16);
}
union FragU { u32 u[4]; b16x8 s; uint4 q; };

__device__ __forceinline__ b16x8 ld_frag_g(const u32* p) {
  FragU f; f.q = *(const uint4*)p; return f.s;
}

// ---------- CPB MLP: one wave per table row ----------
__global__ __launch_bounds__(64) void k_cpb1(
    const float* __restrict__ rpb, const float* __restrict__ w1,
    const float* __restrict__ b1, const float* __restrict__ w2,
    float* __restrict__ tab) {
  int t = blockIdx.x, lane = threadIdx.x;
  float r0 = rpb[t*3], r1 = rpb[t*3+1], r2 = rpb[t*3+2];
  float a[HEADS];
  #pragma unroll
  for (int h = 0; h < HEADS; ++h) a[h] = 0.f;
  #pragma unroll
  for (int kk = 0; kk < 8; ++kk) {
    int k = lane * 8 + kk;
    float hv = fmaf(r0, w1[k*3], fmaf(r1, w1[k*3+1], fmaf(r2, w1[k*3+2], b1[k])));
    hv = fmaxf(hv, 0.f);
    #pragma unroll
    for (int h = 0; h < HEADS; ++h) a[h] = fmaf(hv, w2[h*CPBH + k], a[h]);
  }
  #pragma unroll
  for (int h = 0; h < HEADS; ++h) {
    a[h] += __shfl_xor(a[h], 1);  a[h] += __shfl_xor(a[h], 2);
    a[h] += __shfl_xor(a[h], 4);  a[h] += __shfl_xor(a[h], 8);
    a[h] += __shfl_xor(a[h], 16); a[h] += __shfl_xor(a[h], 32);
  }
  if (lane == 0) {
    #pragma unroll
    for (int h = 0; h < HEADS; ++h) tab[t*HEADS + h] = a[h];
  }
}

// ---------- bias+mask combined table: (nW, H, 64, 64) fp32 ----------
__global__ void k_bm(const float* __restrict__ tab, const int* __restrict__ ridx,
                     const float* __restrict__ mask, float* __restrict__ bm) {
  int idx = blockIdx.x * blockDim.x + threadIdx.x;
  if (idx >= NW * HEADS * 4096) return;
  int ij = idx & 4095;
  int h = (idx >> 12) % HEADS;
  int nw = idx / (HEADS * 4096);
  float v = tab[ridx[ij] * HEADS + h];
  bm[idx] = 16.f / (1.f + __expf(-v)) + mask[nw * 4096 + ij];
}

// ---------- one-time fp32 -> bf16 weight conversion ----------
__global__ void k_wcvt(const float* __restrict__ qkvw, const float* __restrict__ pw,
                       u32* __restrict__ wq, u32* __restrict__ wp) {
  int i = blockIdx.x * blockDim.x + threadIdx.x;
  if (i < 55296) {
    wq[i] = pack2(qkvw[2*i], qkvw[2*i+1]);
  } else if (i < 55296 + 18432) {
    int j = i - 55296;
    wp[j] = pack2(pw[2*j], pw[2*j+1]);
  }
}

// ---------- QKV: MFMA, A = bf16 W rows, B = x^T from LDS ----------
__global__ __launch_bounds__(384) void k_qkv(
    const float* __restrict__ x, const u32* __restrict__ wq,
    const float* __restrict__ bias,
    u32* __restrict__ qo, u32* __restrict__ ko, u32* __restrict__ vT) {
  __shared__ u32 xl[NTOK * 101];   // stride 101 dwords -> ~conflict-free b128 reads
  const int tid = threadIdx.x;
  const int b = blockIdx.x;
  const float4* xg = (const float4*)(x + (size_t)b * (NTOK * DIM));
  for (int i = tid; i < (NTOK * DIM) / 4; i += 384) {
    float4 v = xg[i];
    int flat = i * 4, tok = flat / DIM, k = flat % DIM;
    xl[tok*101 + k/2]     = pack2(v.x, v.y);
    xl[tok*101 + k/2 + 1] = pack2(v.z, v.w);
  }
  __syncthreads();
  const int lane = tid & 63;
  const int wv = tid >> 6;         // 0..5
  const int m = lane & 15;
  const int qd = lane >> 4;
  const int sel = wv >> 1;         // 0=q 1=k 2=v
  u32* dst = (sel == 0) ? qo : (sel == 1) ? ko : vT;
  #pragma unroll 1
  for (int p = 0; p < 3; ++p) {
    const int h = (wv & 1) * 3 + p;
    const int jbase = wv * 96 + p * 32;
    b16x8 afr[2][6];
    float bv[2][4];
    #pragma unroll
    for (int half = 0; half < 2; ++half) {
      const u32* wp = wq + (size_t)(jbase + half*16 + m) * 96;
      #pragma unroll
      for (int ks = 0; ks < 6; ++ks) afr[half][ks] = ld_frag_g(wp + ks*16 + qd*4);
      #pragma unroll
      for (int r = 0; r < 4; ++r) bv[half][r] = bias[jbase + half*16 + qd*4 + r];
    }
    const size_t bh1024 = ((size_t)b * HEADS + h) * 1024;
    #pragma unroll 1
    for (int tp = 0; tp < 2; ++tp) {
      f32x4 acc[2][2];
      #pragma unroll
      for (int tt = 0; tt < 2; ++tt) {
        acc[tt][0] = (f32x4){0.f,0.f,0.f,0.f};
        acc[tt][1] = (f32x4){0.f,0.f,0.f,0.f};
      }
      #pragma unroll
      for (int ks = 0; ks < 6; ++ks) {
        #pragma unroll
        for (int tt = 0; tt < 2; ++tt) {
          b16x8 bfr = *(const b16x8*)(&xl[((tp*2+tt)*16 + m)*101 + ks*16 + qd*4]);
          acc[tt][0] = __builtin_amdgcn_mfma_f32_16x16x32_bf16(afr[0][ks], bfr, acc[tt][0], 0,0,0);
          acc[tt][1] = __builtin_amdgcn_mfma_f32_16x16x32_bf16(afr[1][ks], bfr, acc[tt][1], 0,0,0);
        }
      }
      #pragma unroll
      for (int tt = 0; tt < 2; ++tt) {
        const int t = tp*2 + tt;
        f32x4 acc0 = acc[tt][0], acc1 = acc[tt][1];
        #pragma unroll
        for (int r = 0; r < 4; ++r) { acc0[r] += bv[0][r]; acc1[r] += bv[1][r]; }
        if (sel < 2) {
          float ss = 0.f;
          #pragma unroll
          for (int r = 0; r < 4; ++r) ss = fmaf(acc0[r],acc0[r], fmaf(acc1[r],acc1[r], ss));
          ss += __shfl_xor(ss, 16);
          ss += __shfl_xor(ss, 32);
          float inv = 1.f / fmaxf(sqrtf(ss), 1e-12f);
          #pragma unroll
          for (int r = 0; r < 4; ++r) { acc0[r] *= inv; acc1[r] *= inv; }
          int tok = t*16 + m;
          u32* o = dst + bh1024 + tok*16;
          *(uint2*)(o + qd*2)     = make_uint2(pack2(acc0[0],acc0[1]), pack2(acc0[2],acc0[3]));
          *(uint2*)(o + 8 + qd*2) = make_uint2(pack2(acc1[0],acc1[1]), pack2(acc1[2],acc1[3]));
        } else {
          float p0[8];
          #pragma unroll
          for (int r = 0; r < 4; ++r) { p0[r] = acc0[r]; p0[4+r] = acc1[r]; }
          float pr[8];
          #pragma unroll
          for (int e = 0; e < 8; ++e) pr[e] = __shfl_xor(p0[e], 1);
          if ((m & 1) == 0) {
            #pragma unroll
            for (int e = 0; e < 8; ++e) {
              int d = (e >> 2)*16 + qd*4 + (e & 3);
              dst[bh1024 + d*32 + (t*16 + m)/2] = pack2(p0[e], pr[e]);
            }
          }
        }
      }
    }
  }
}

// ---------- fused attention + projection, one block per window ----------
__global__ __launch_bounds__(384) void k_attn_proj(
    const u32* __restrict__ qo, const u32* __restrict__ ko, const u32* __restrict__ vT,
    const float* __restrict__ bm, const float* __restrict__ ls,
    const u32* __restrict__ wp, const float* __restrict__ pb,
    float* __restrict__ out) {
  __shared__ u32 pbuf[HEADS][64 * 35];  // 53,760 B
  __shared__ u32 aol[64 * 99];          // 25,344 B  (total 79.1 KB -> 2 blocks/CU)
  const int tid = threadIdx.x;
  const int b = blockIdx.x;
  const int h = tid >> 6;   // wave = head
  const int lane = tid & 63;
  const int m = lane & 15, qd = lane >> 4;
  const size_t bh1024 = ((size_t)b * HEADS + h) * 1024;

  b16x8 qfr[4], kfr[4];
  #pragma unroll
  for (int mt = 0; mt < 4; ++mt) qfr[mt] = ld_frag_g(qo + bh1024 + (mt*16 + m)*16 + qd*4);
  #pragma unroll
  for (int ct = 0; ct < 4; ++ct) kfr[ct] = ld_frag_g(ko + bh1024 + (ct*16 + m)*16 + qd*4);

  f32x4 s[4][4];
  #pragma unroll
  for (int mt = 0; mt < 4; ++mt)
    #pragma unroll
    for (int ct = 0; ct < 4; ++ct) {
      f32x4 z = {0.f,0.f,0.f,0.f};
      s[mt][ct] = __builtin_amdgcn_mfma_f32_16x16x32_bf16(qfr[mt], kfr[ct], z, 0,0,0);
    }

  const float sc = __expf(fminf(ls[h], 4.60517019f));
  const float* bmp = bm + ((size_t)(b & 63) * HEADS + h) * 4096;
  #pragma unroll
  for (int mt = 0; mt < 4; ++mt)
    #pragma unroll
    for (int ct = 0; ct < 4; ++ct) {
      #pragma unroll
      for (int r = 0; r < 4; ++r) {
        int row = mt*16 + qd*4 + r, col = ct*16 + m;
        s[mt][ct][r] = fmaf(s[mt][ct][r], sc, bmp[row*64 + col]);
      }
    }
  float rinv[4][4];
  u32* pbw = pbuf[h];
  #pragma unroll
  for (int mt = 0; mt < 4; ++mt) {
    #pragma unroll
    for (int r = 0; r < 4; ++r) {
      float mm = s[mt][0][r];
      #pragma unroll
      for (int ct = 1; ct < 4; ++ct) mm = fmaxf(mm, s[mt][ct][r]);
      mm = fmaxf(mm, __shfl_xor(mm, 1)); mm = fmaxf(mm, __shfl_xor(mm, 2));
      mm = fmaxf(mm, __shfl_xor(mm, 4)); mm = fmaxf(mm, __shfl_xor(mm, 8));
      float l = 0.f;
      #pragma unroll
      for (int ct = 0; ct < 4; ++ct) { s[mt][ct][r] = __expf(s[mt][ct][r] - mm); l += s[mt][ct][r]; }
      l += __shfl_xor(l, 1); l += __shfl_xor(l, 2);
      l += __shfl_xor(l, 4); l += __shfl_xor(l, 8);
      rinv[mt][r] = 1.f / l;
      int row = mt*16 + qd*4 + r;
      #pragma unroll
      for (int ct = 0; ct < 4; ++ct) {
        float pv = s[mt][ct][r];
        float pn = __shfl_xor(pv, 1);
        if ((m & 1) == 0) pbw[row*35 + ct*8 + (m >> 1)] = pack2(pv, pn);
      }
    }
  }
  // PV
  b16x8 vfr[2][2];
  #pragma unroll
  for (int nt = 0; nt < 2; ++nt)
    #pragma unroll
    for (int ks = 0; ks < 2; ++ks)
      vfr[nt][ks] = ld_frag_g(vT + bh1024 + (nt*16 + m)*32 + ks*16 + qd*4);
  #pragma unroll
  for (int mt = 0; mt < 4; ++mt) {
    b16x8 pa0 = *(const b16x8*)(&pbw[(mt*16 + m)*35 + qd*4]);
    b16x8 pa1 = *(const b16x8*)(&pbw[(mt*16 + m)*35 + 16 + qd*4]);
    #pragma unroll
    for (int nt = 0; nt < 2; ++nt) {
      f32x4 o = {0.f,0.f,0.f,0.f};
      o = __builtin_amdgcn_mfma_f32_16x16x32_bf16(pa0, vfr[nt][0], o, 0,0,0);
      o = __builtin_amdgcn_mfma_f32_16x16x32_bf16(pa1, vfr[nt][1], o, 0,0,0);
      #pragma unroll
      for (int r = 0; r < 4; ++r) {
        float val = o[r] * rinv[mt][r];
        float pn = __shfl_xor(val, 1);
        if ((m & 1) == 0) {
          int row = mt*16 + qd*4 + r;
          aol[row*99 + h*16 + nt*8 + (m >> 1)] = pack2(val, pn);
        }
      }
    }
  }
  __syncthreads();
  // projection phase: wave wv handles output cols wv*32..wv*32+31
  const int wv = h;
  b16x8 afr[2][6];
  float bv[2][4];
  #pragma unroll
  for (int jj = 0; jj < 2; ++jj) {
    const u32* wrow = wp + (size_t)((wv*2 + jj)*16 + m) * 96;
    #pragma unroll
    for (int ks = 0; ks < 6; ++ks) afr[jj][ks] = ld_frag_g(wrow + ks*16 + qd*4);
    #pragma unroll
    for (int r = 0; r < 4; ++r) bv[jj][r] = pb[(wv*2 + jj)*16 + qd*4 + r];
  }
  #pragma unroll 1
  for (int t = 0; t < 4; ++t) {
    f32x4 acc0 = {0.f,0.f,0.f,0.f}, acc1 = {0.f,0.f,0.f,0.f};
    #pragma unroll
    for (int ks = 0; ks < 6; ++ks) {
      b16x8 bfr = *(const b16x8*)(&aol[(t*16 + m)*99 + ks*16 + qd*4]);
      acc0 = __builtin_amdgcn_mfma_f32_16x16x32_bf16(afr[0][ks], bfr, acc0, 0,0,0);
      acc1 = __builtin_amdgcn_mfma_f32_16x16x32_bf16(afr[1][ks], bfr, acc1, 0,0,0);
    }
    float* op = out + ((size_t)b*64 + t*16 + m) * DIM;
    *(float4*)(op + (wv*2+0)*16 + qd*4) =
        make_float4(acc0[0]+bv[0][0], acc0[1]+bv[0][1], acc0[2]+bv[0][2], acc0[3]+bv[0][3]);
    *(float4*)(op + (wv*2+1)*16 + qd*4) =
        make_float4(acc1[0]+bv[1][0], acc1[1]+bv[1][1], acc1[2]+bv[1][2], acc1[3]+bv[1][3]);
  }
}

extern "C" void kernel_launch(void* const* d_in, const int* in_sizes, int n_in,
                              void* d_out, int out_size, void* d_ws, size_t ws_size,
                              hipStream_t stream) {
  const float* x    = (const float*)d_in[0];
  const float* mask = (const float*)d_in[1];
  const float* rpb  = (const float*)d_in[2];
  const int*   ridx = (const int*)d_in[3];
  const float* w1   = (const float*)d_in[4];
  const float* b1   = (const float*)d_in[5];
  const float* w2   = (const float*)d_in[6];
  const float* qkvw = (const float*)d_in[7];
  const float* qkvb = (const float*)d_in[8];
  const float* pw   = (const float*)d_in[9];
  const float* pb   = (const float*)d_in[10];
  const float* ls   = (const float*)d_in[11];
  float* out = (float*)d_out;

  char* ws = (char*)d_ws;
  const size_t QS = (size_t)BATCH * HEADS * NTOK * HD * 2;  // 50,331,648 B
  u32* qo = (u32*)(ws);
  u32* ko = (u32*)(ws + QS);
  u32* vT = (u32*)(ws + 2 * QS);
  float* btab = (float*)(ws + 3 * QS);                   // 16 KB slot
  float* bm   = (float*)(ws + 3 * QS + 16384);           // 6,291,456 B
  u32* wq = (u32*)(ws + 3 * QS + 16384 + 6291456);       // 221,184 B
  u32* wp = (u32*)(ws + 3 * QS + 16384 + 6291456 + 221184); // 73,728 B
  // total: 3*50331648 + 16384 + 6291456 + 221184 + 73728 = 157,597,696 B

  k_cpb1<<<TBL, 64, 0, stream>>>(rpb, w1, b1, w2, btab);
  k_wcvt<<<(73728 + 255) / 256, 256, 0, stream>>>(qkvw, pw, wq, wp);
  k_bm<<<(NW * HEADS * 4096 + 255) / 256, 256, 0, stream>>>(btab, ridx, mask, bm);
  k_qkv<<<BATCH, 384, 0, stream>>>(x, wq, qkvb, qo, ko, vT);
  k_attn_proj<<<BATCH, 384, 0, stream>>>(qo, ko, vT, bm, ls, wp, pb, out);
}